// Round 3
// baseline (6830.085 us; speedup 1.0000x reference)
//
#include <hip/hip_runtime.h>
#include <math.h>

// Problem constants: B=4, T=1024, D=512, G=4*D=2048, V=32000
// Workspace layout (56 MB):
//   [0,8M)    x / hs2   [4096,512] f32  (x dead after xg1 GEMM; reused as hs2)
//   [8M,40M)  xg1       [4096,2048] f32
//   [40M,48M) h1c       [T][512][4] f32  sentinel-polled comm buffer, layer-1 h
//   [48M,56M) h2c       [T][512][4] f32  sentinel-polled comm buffer, layer-2 h

#define TSEQ 1024
#define DIM  512
#define GDIM 2048

typedef unsigned uint4v __attribute__((ext_vector_type(4)));
typedef float    f4v    __attribute__((ext_vector_type(4)));

// sentinel = memset 0x7F7F7F7F = 3.39e38f; real |h| < 1, so "any component > 2"
// detects an unwritten granule (float max3 check, 3 VALU ops).
__device__ __forceinline__ float fmax4(f4v a) {
    return fmaxf(fmaxf(a.x, a.y), fmaxf(a.z, a.w));
}

// Agent-scope (sc1 bypasses the non-coherent per-XCD L2s) 16B sentinel poll.
__device__ __forceinline__ f4v poll16(const unsigned* p) {
    uint4v u; f4v f;
    do {
        asm volatile("global_load_dwordx4 %0, %1, off sc1\n\t"
                     "s_waitcnt vmcnt(0)"
                     : "=v"(u) : "v"(p) : "memory");
        f = __builtin_bit_cast(f4v, u);
    } while (fmax4(f) > 2.0f);
    return f;
}

// Two concurrent 16B polls (one round-trip when both ready). Monotonic
// sentinel->value transitions make redundant reloads harmless.
__device__ __forceinline__ void poll2(const unsigned* p, const unsigned* q,
                                      f4v* o1, f4v* o2) {
    uint4v u, v; f4v a, b;
    do {
        asm volatile("global_load_dwordx4 %0, %2, off sc1\n\t"
                     "global_load_dwordx4 %1, %3, off sc1\n\t"
                     "s_waitcnt vmcnt(0)"
                     : "=v"(u), "=v"(v) : "v"(p), "v"(q) : "memory");
        a = __builtin_bit_cast(f4v, u);
        b = __builtin_bit_cast(f4v, v);
    } while (fmaxf(fmax4(a), fmax4(b)) > 2.0f);
    *o1 = a; *o2 = b;
}

// fast sigmoid/tanh via v_exp_f32 + v_rcp_f32 (~1e-7 rel err, vs libm ~80 ops)
__device__ __forceinline__ float fsigmoid(float x) {
    return __builtin_amdgcn_rcpf(1.0f + __expf(-x));
}
__device__ __forceinline__ float ftanh_(float x) {
    return 1.0f - 2.0f * __builtin_amdgcn_rcpf(1.0f + __expf(2.0f * x));
}

// ---------------------------------------------------------------------------
// Embedding lookup with shift-right
// ---------------------------------------------------------------------------
__global__ void embed_kernel(const int* __restrict__ tokens,
                             const float* __restrict__ embed,
                             float* __restrict__ x)
{
    const int row = blockIdx.x;          // b*T + t
    const int b = row >> 10;
    const int t = row & 1023;
    const int tok = (t == 0) ? 0 : tokens[b * TSEQ + t - 1];
    const float4* src = (const float4*)(embed + (size_t)tok * DIM);
    float4* dst = (float4*)(x + (size_t)row * DIM);
    dst[threadIdx.x] = src[threadIdx.x];
}

// ---------------------------------------------------------------------------
// fp32 GEMM with bias: C[M,N] = A[M,K] @ B[K,N] + bias[N]   (unchanged)
// ---------------------------------------------------------------------------
__global__ __launch_bounds__(256) void gemm_bias_f32(
    const float* __restrict__ A, const float* __restrict__ Bm,
    const float* __restrict__ bias, float* __restrict__ C,
    int M, int N, int K)
{
    constexpr int BK = 16;
    __shared__ float As[BK][128 + 4];
    __shared__ float Bs[BK][128 + 4];

    const int tid = threadIdx.x;
    const int m0 = blockIdx.y * 128;
    const int n0 = blockIdx.x * 128;
    const int tm = (tid >> 4) << 3;
    const int tn = (tid & 15) << 3;

    const int a_r = tid >> 2;
    const int a_c = (tid & 3) << 2;
    const int b_r = tid >> 5;
    const int b_c = (tid & 31) << 2;

    float acc[8][8] = {};

    for (int k0 = 0; k0 < K; k0 += BK) {
        const float4 av0 = *(const float4*)&A[(size_t)(m0 + a_r) * K + k0 + a_c];
        const float4 av1 = *(const float4*)&A[(size_t)(m0 + a_r + 64) * K + k0 + a_c];
        const float4 bv0 = *(const float4*)&Bm[(size_t)(k0 + b_r) * N + n0 + b_c];
        const float4 bv1 = *(const float4*)&Bm[(size_t)(k0 + b_r + 8) * N + n0 + b_c];
        __syncthreads();
        As[a_c + 0][a_r] = av0.x;  As[a_c + 1][a_r] = av0.y;
        As[a_c + 2][a_r] = av0.z;  As[a_c + 3][a_r] = av0.w;
        As[a_c + 0][a_r + 64] = av1.x;  As[a_c + 1][a_r + 64] = av1.y;
        As[a_c + 2][a_r + 64] = av1.z;  As[a_c + 3][a_r + 64] = av1.w;
        *(float4*)&Bs[b_r][b_c] = bv0;
        *(float4*)&Bs[b_r + 8][b_c] = bv1;
        __syncthreads();

        #pragma unroll
        for (int kk = 0; kk < BK; ++kk) {
            float a[8], bf[8];
            *(float4*)&a[0]  = *(const float4*)&As[kk][tm];
            *(float4*)&a[4]  = *(const float4*)&As[kk][tm + 4];
            *(float4*)&bf[0] = *(const float4*)&Bs[kk][tn];
            *(float4*)&bf[4] = *(const float4*)&Bs[kk][tn + 4];
            #pragma unroll
            for (int i = 0; i < 8; ++i)
                #pragma unroll
                for (int jx = 0; jx < 8; ++jx)
                    acc[i][jx] += a[i] * bf[jx];
        }
    }

    float bv[8];
    #pragma unroll
    for (int jx = 0; jx < 8; ++jx) bv[jx] = bias[n0 + tn + jx];

    #pragma unroll
    for (int i = 0; i < 8; ++i) {
        float* crow = C + (size_t)(m0 + tm + i) * N + (n0 + tn);
        float4 o0, o1;
        o0.x = acc[i][0] + bv[0]; o0.y = acc[i][1] + bv[1];
        o0.z = acc[i][2] + bv[2]; o0.w = acc[i][3] + bv[3];
        o1.x = acc[i][4] + bv[4]; o1.y = acc[i][5] + bv[5];
        o1.z = acc[i][6] + bv[6]; o1.w = acc[i][7] + bv[7];
        *(float4*)&crow[0] = o0;
        *(float4*)&crow[4] = o1;
    }
}

// ---------------------------------------------------------------------------
// Persistent 2-layer pipelined LSTM. 128 WGs x 512 threads.
//   WGs 0..63   layer 1: own h1-dims [8wg,8wg+8); Wh0 col-pair slice in regs.
//   WGs 64..127 layer 2: input = concat[h1[t], h2[t-1]] (1024 dims), fused
//               Wx1/Wh1 col-pair slice in regs, both h polled in ONE round trip.
// MAC roles: tid -> (s=tid>>4 row-chunk, jp=tid&15 col-pair {jp, jp+16}).
// Combine/finish roles: tid<128 -> (batch=tid>>5, gate-col=tid&31); activations
// parallel on 128 lanes; gates exchanged via 3x shfl_xor; c-state in lanes
// with col<8. Only 2 barriers per step.
// ---------------------------------------------------------------------------
__global__ __launch_bounds__(512, 1) void lstm2_kernel(
    const float* __restrict__ xg1, const float* __restrict__ Wh0,
    const float* __restrict__ Wx1, const float* __restrict__ Wh1,
    const float* __restrict__ b1,
    float* __restrict__ h1c, float* __restrict__ h2c,
    float* __restrict__ hs2)
{
    const int layer = blockIdx.x >> 6;
    const int wg    = blockIdx.x & 63;
    const int tid   = threadIdx.x;
    const int dbase = wg * 8;

    // MAC role
    const int s   = tid >> 4;                             // 0..31
    const int jp  = tid & 15;                             // col pair {jp, jp+16}
    const int wcA = (jp >> 3) * DIM + dbase + (jp & 7);   // cols 0..15  (i,f)
    const int wcB = wcA + 2 * DIM;                        // cols 16..31 (g,o)

    // combine/finisher role (tid<128)
    const int cb   = tid >> 5;                            // batch
    const int cj   = tid & 31;                            // gate col
    const int cwc  = (cj >> 3) * DIM + dbase + (cj & 7);
    const int cgrp = cj >> 3;                             // 0:i 1:f 2:g 3:o

    __shared__ f4v  hC[2 * DIM];                          // 16KB: [h1 | h2] (L2)
    __shared__ float partA[4][32][16];                    // cols 0..15
    __shared__ float partB[4][32][16];                    // cols 16..31

    // weights -> registers (one-time)
    float w0[32], w1[32];
    if (layer == 0) {
        #pragma unroll
        for (int r = 0; r < 16; ++r) {
            w0[r] = Wh0[(size_t)(s * 16 + r) * GDIM + wcA];
            w1[r] = Wh0[(size_t)(s * 16 + r) * GDIM + wcB];
        }
    } else {
        const float* W   = (s < 16) ? Wx1 : Wh1;
        const int   roff = (s < 16) ? s * 32 : s * 32 - 512;
        #pragma unroll
        for (int r = 0; r < 32; ++r) {
            w0[r] = W[(size_t)(roff + r) * GDIM + wcA];
            w1[r] = W[(size_t)(roff + r) * GDIM + wcB];
        }
    }
    const float bias2 = (layer && tid < 128) ? b1[cwc] : 0.f;

    float c_reg = 0.f;   // c-state, valid in lanes (tid<128 && cgrp==0)

    const unsigned* h1u = (const unsigned*)h1c;
    const unsigned* h2u = (const unsigned*)h2c;

    if (layer == 0) {
        for (int t = 0; t < TSEQ; ++t) {
            float xgv = 0.f;
            if (tid < 128)
                xgv = xg1[((size_t)cb * TSEQ + t) * GDIM + cwc];

            if (t > 0) hC[tid] = poll16(h1u + ((size_t)(t - 1) * DIM + tid) * 4);
            else       hC[tid] = f4v{0.f, 0.f, 0.f, 0.f};
            __syncthreads();

            f4v acc0 = {0.f, 0.f, 0.f, 0.f}, acc1 = {0.f, 0.f, 0.f, 0.f};
            const f4v* hp = &hC[s * 16];
            #pragma unroll
            for (int r = 0; r < 16; ++r) {
                const f4v v = hp[r];
                acc0 += v * w0[r];
                acc1 += v * w1[r];
            }
            #pragma unroll
            for (int b = 0; b < 4; ++b) {
                partA[b][s][jp] = acc0[b];
                partB[b][s][jp] = acc1[b];
            }
            __syncthreads();

            if (tid < 128) {
                float sum = xgv;
                const float* P = (cj < 16) ? &partA[cb][0][cj] : &partB[cb][0][cj - 16];
                #pragma unroll
                for (int s2 = 0; s2 < 32; ++s2) sum += P[s2 * 16];
                const float xs = (cgrp == 2) ? 2.f * sum : sum;
                const float sg = fsigmoid(xs);
                const float y  = (cgrp == 2) ? 2.f * sg - 1.f : sg;   // tanh for g
                const float f_ = __shfl_xor(y, 8);
                const float g_ = __shfl_xor(y, 16);
                const float o_ = __shfl_xor(f_, 16);
                if (cgrp == 0) {      // lanes cj<8: i=y, f=f_, g=g_, o=o_
                    c_reg = f_ * c_reg + y * g_;
                    const float hval = o_ * ftanh_(c_reg);
                    __hip_atomic_store(&h1c[((size_t)t * DIM + dbase + cj) * 4 + cb],
                                       hval, __ATOMIC_RELAXED, __HIP_MEMORY_SCOPE_AGENT);
                }
            }
        }
    } else {
        for (int t = 0; t < TSEQ; ++t) {
            if (t > 0) {
                f4v a, b;
                poll2(h1u + ((size_t)t * DIM + tid) * 4,
                      h2u + ((size_t)(t - 1) * DIM + tid) * 4, &a, &b);
                hC[tid]       = a;
                hC[DIM + tid] = b;
            } else {
                hC[tid]       = poll16(h1u + ((size_t)t * DIM + tid) * 4);
                hC[DIM + tid] = f4v{0.f, 0.f, 0.f, 0.f};
            }
            __syncthreads();

            f4v acc0 = {0.f, 0.f, 0.f, 0.f}, acc1 = {0.f, 0.f, 0.f, 0.f};
            const f4v* hp = &hC[s * 32];
            #pragma unroll
            for (int r = 0; r < 32; ++r) {
                const f4v v = hp[r];
                acc0 += v * w0[r];
                acc1 += v * w1[r];
            }
            #pragma unroll
            for (int b = 0; b < 4; ++b) {
                partA[b][s][jp] = acc0[b];
                partB[b][s][jp] = acc1[b];
            }
            __syncthreads();

            if (tid < 128) {
                float sum = bias2;
                const float* P = (cj < 16) ? &partA[cb][0][cj] : &partB[cb][0][cj - 16];
                #pragma unroll
                for (int s2 = 0; s2 < 32; ++s2) sum += P[s2 * 16];
                const float xs = (cgrp == 2) ? 2.f * sum : sum;
                const float sg = fsigmoid(xs);
                const float y  = (cgrp == 2) ? 2.f * sg - 1.f : sg;
                const float f_ = __shfl_xor(y, 8);
                const float g_ = __shfl_xor(y, 16);
                const float o_ = __shfl_xor(f_, 16);
                if (cgrp == 0) {
                    c_reg = f_ * c_reg + y * g_;
                    const float hval = o_ * ftanh_(c_reg);
                    __hip_atomic_store(&h2c[((size_t)t * DIM + dbase + cj) * 4 + cb],
                                       hval, __ATOMIC_RELAXED, __HIP_MEMORY_SCOPE_AGENT);
                    hs2[((size_t)cb * TSEQ + t) * DIM + dbase + cj] = hval;
                }
            }
        }
    }
}

// ---------------------------------------------------------------------------
extern "C" void kernel_launch(void* const* d_in, const int* in_sizes, int n_in,
                              void* d_out, int out_size, void* d_ws, size_t ws_size,
                              hipStream_t stream)
{
    const int*   tokens = (const int*)d_in[0];
    const float* embed  = (const float*)d_in[1];
    const float* Wx0    = (const float*)d_in[2];
    const float* Wh0    = (const float*)d_in[3];
    const float* b0     = (const float*)d_in[4];
    const float* Wx1    = (const float*)d_in[5];
    const float* Wh1    = (const float*)d_in[6];
    const float* b1     = (const float*)d_in[7];
    const float* Wout   = (const float*)d_in[8];
    const float* bout   = (const float*)d_in[9];
    float* out = (float*)d_out;

    char* ws = (char*)d_ws;
    float* x   = (float*)(ws);                      // reused as hs2 after GEMM1
    float* xg1 = (float*)(ws + ((size_t)8u << 20));
    float* h1c = (float*)(ws + ((size_t)40u << 20));
    float* h2c = (float*)(ws + ((size_t)48u << 20));
    float* hs2 = x;

    // sentinel-init both comm buffers (contiguous 16MB)
    hipMemsetAsync(ws + ((size_t)40u << 20), 0x7F, (size_t)16u << 20, stream);

    embed_kernel<<<dim3(4096), dim3(128), 0, stream>>>(tokens, embed, x);
    gemm_bias_f32<<<dim3(16, 32), dim3(256), 0, stream>>>(x, Wx0, b0, xg1, 4096, 2048, 512);
    lstm2_kernel<<<dim3(128), dim3(512), 0, stream>>>(xg1, Wh0, Wx1, Wh1, b1, h1c, h2c, hs2);
    gemm_bias_f32<<<dim3(250, 32), dim3(256), 0, stream>>>(hs2, Wout, bout, out, 4096, 32000, 512);
}

// Round 4
// 3775.660 us; speedup vs baseline: 1.8090x; 1.8090x over previous
//
#include <hip/hip_runtime.h>
#include <math.h>

// Problem constants: B=4, T=1024, D=512, G=4*D=2048, V=32000
// Workspace layout:
//   [0,8M)     x / hs2   [4096,512] f32
//   [8M,40M)   xg1       [4096,2048] f32
//   [40M,48M)  h1c       [T][512][4] f32  sentinel comm buffer L1
//   [48M,56M)  h2c       [T][512][4] f32  sentinel comm buffer L2
//   [56M,68M)  A'        [4096][1536] bf16 (split-triple)   } only if
//   [68M,~162M) W'       [32000][1536] bf16 (split-triple)  } ws_size >= 162MiB

#define TSEQ 1024
#define DIM  512
#define GDIM 2048
#define VOC  32000
#define SENT 0x7F7F7F7Fu

typedef unsigned uint4v __attribute__((ext_vector_type(4)));
typedef float    f4v    __attribute__((ext_vector_type(4)));
typedef short    short8 __attribute__((ext_vector_type(8)));
typedef float    f32x4  __attribute__((ext_vector_type(4)));

// Agent-scope (sc1 bypasses the non-coherent per-XCD L2s) 16B sentinel poll.
__device__ __forceinline__ uint4v poll_load16(const unsigned* p) {
    uint4v v;
    asm volatile("global_load_dwordx4 %0, %1, off sc1\n\t"
                 "s_waitcnt vmcnt(0)"
                 : "=v"(v) : "v"(p) : "memory");
    return v;
}
__device__ __forceinline__ void poll_load16x2(const unsigned* p, const unsigned* q,
                                              uint4v* a, uint4v* b) {
    asm volatile("global_load_dwordx4 %0, %2, off sc1\n\t"
                 "global_load_dwordx4 %1, %3, off sc1\n\t"
                 "s_waitcnt vmcnt(0)"
                 : "=v"(*a), "=v"(*b) : "v"(p), "v"(q) : "memory");
}

// fast sigmoid/tanh via v_exp_f32 + v_rcp_f32 (~1e-6 abs err)
__device__ __forceinline__ float fsig(float x) {
    return __builtin_amdgcn_rcpf(1.0f + __expf(-x));
}
__device__ __forceinline__ float ftanh_(float x) {
    return 1.0f - 2.0f * __builtin_amdgcn_rcpf(1.0f + __expf(2.0f * x));
}

// f32 -> bf16 RNE, and back
__device__ __forceinline__ unsigned short f2bf(float x) {
    unsigned u = __builtin_bit_cast(unsigned, x);
    return (unsigned short)((u + 0x7FFFu + ((u >> 16) & 1u)) >> 16);
}
__device__ __forceinline__ float bf2f(unsigned short h) {
    return __builtin_bit_cast(float, (unsigned)h << 16);
}

// ---------------------------------------------------------------------------
// Embedding lookup with shift-right
// ---------------------------------------------------------------------------
__global__ void embed_kernel(const int* __restrict__ tokens,
                             const float* __restrict__ embed,
                             float* __restrict__ x)
{
    const int row = blockIdx.x;
    const int b = row >> 10;
    const int t = row & 1023;
    const int tok = (t == 0) ? 0 : tokens[b * TSEQ + t - 1];
    const float4* src = (const float4*)(embed + (size_t)tok * DIM);
    float4* dst = (float4*)(x + (size_t)row * DIM);
    dst[threadIdx.x] = src[threadIdx.x];
}

// ---------------------------------------------------------------------------
// fp32 GEMM with bias (xg1 + fallback logits)
// ---------------------------------------------------------------------------
__global__ __launch_bounds__(256) void gemm_bias_f32(
    const float* __restrict__ A, const float* __restrict__ Bm,
    const float* __restrict__ bias, float* __restrict__ C,
    int M, int N, int K)
{
    constexpr int BK = 16;
    __shared__ float As[BK][128 + 4];
    __shared__ float Bs[BK][128 + 4];

    const int tid = threadIdx.x;
    const int m0 = blockIdx.y * 128;
    const int n0 = blockIdx.x * 128;
    const int tm = (tid >> 4) << 3;
    const int tn = (tid & 15) << 3;

    const int a_r = tid >> 2;
    const int a_c = (tid & 3) << 2;
    const int b_r = tid >> 5;
    const int b_c = (tid & 31) << 2;

    float acc[8][8] = {};

    for (int k0 = 0; k0 < K; k0 += BK) {
        const float4 av0 = *(const float4*)&A[(size_t)(m0 + a_r) * K + k0 + a_c];
        const float4 av1 = *(const float4*)&A[(size_t)(m0 + a_r + 64) * K + k0 + a_c];
        const float4 bv0 = *(const float4*)&Bm[(size_t)(k0 + b_r) * N + n0 + b_c];
        const float4 bv1 = *(const float4*)&Bm[(size_t)(k0 + b_r + 8) * N + n0 + b_c];
        __syncthreads();
        As[a_c + 0][a_r] = av0.x;  As[a_c + 1][a_r] = av0.y;
        As[a_c + 2][a_r] = av0.z;  As[a_c + 3][a_r] = av0.w;
        As[a_c + 0][a_r + 64] = av1.x;  As[a_c + 1][a_r + 64] = av1.y;
        As[a_c + 2][a_r + 64] = av1.z;  As[a_c + 3][a_r + 64] = av1.w;
        *(float4*)&Bs[b_r][b_c] = bv0;
        *(float4*)&Bs[b_r + 8][b_c] = bv1;
        __syncthreads();

        #pragma unroll
        for (int kk = 0; kk < BK; ++kk) {
            float a[8], bf[8];
            *(float4*)&a[0]  = *(const float4*)&As[kk][tm];
            *(float4*)&a[4]  = *(const float4*)&As[kk][tm + 4];
            *(float4*)&bf[0] = *(const float4*)&Bs[kk][tn];
            *(float4*)&bf[4] = *(const float4*)&Bs[kk][tn + 4];
            #pragma unroll
            for (int i = 0; i < 8; ++i)
                #pragma unroll
                for (int jx = 0; jx < 8; ++jx)
                    acc[i][jx] += a[i] * bf[jx];
        }
    }

    float bv[8];
    #pragma unroll
    for (int jx = 0; jx < 8; ++jx) bv[jx] = bias[n0 + tn + jx];

    #pragma unroll
    for (int i = 0; i < 8; ++i) {
        float* crow = C + (size_t)(m0 + tm + i) * N + (n0 + tn);
        float4 o0, o1;
        o0.x = acc[i][0] + bv[0]; o0.y = acc[i][1] + bv[1];
        o0.z = acc[i][2] + bv[2]; o0.w = acc[i][3] + bv[3];
        o1.x = acc[i][4] + bv[4]; o1.y = acc[i][5] + bv[5];
        o1.z = acc[i][6] + bv[6]; o1.w = acc[i][7] + bv[7];
        *(float4*)&crow[0] = o0;
        *(float4*)&crow[4] = o1;
    }
}

// ---------------------------------------------------------------------------
// Persistent 2-layer pipelined LSTM — round-2 structure (known 3.28ms),
// only change: fast gate activations (v_exp/v_rcp) replacing libm.
// ---------------------------------------------------------------------------
__global__ __launch_bounds__(512, 1) void lstm2_kernel(
    const float* __restrict__ xg1, const float* __restrict__ Wh0,
    const float* __restrict__ Wx1, const float* __restrict__ Wh1,
    const float* __restrict__ b1,
    float* __restrict__ h1c, float* __restrict__ h2c,
    float* __restrict__ hs2)
{
    const int layer = blockIdx.x >> 6;
    const int wg    = blockIdx.x & 63;
    const int tid   = threadIdx.x;
    const int dbase = wg * 8;
    const int j = tid & 31;
    const int s = tid >> 5;
    const int wcol = (j >> 3) * DIM + dbase + (j & 7);

    __shared__ f4v  hA[DIM];
    __shared__ f4v  hB[DIM];
    __shared__ float part[16][4][32];
    __shared__ float gate_lds[4][32];

    float wr[32], wx[32];
    {
        const float* Wrec = layer ? Wh1 : Wh0;
        #pragma unroll
        for (int r = 0; r < 32; ++r)
            wr[r] = Wrec[(size_t)(s * 32 + r) * GDIM + wcol];
        if (layer) {
            #pragma unroll
            for (int r = 0; r < 32; ++r)
                wx[r] = Wx1[(size_t)(s * 32 + r) * GDIM + wcol];
        }
    }
    float bias2 = 0.f;
    if (layer && tid < 128) bias2 = b1[wcol];

    float c_reg = 0.f;
    const unsigned* h1u = (const unsigned*)h1c;
    const unsigned* h2u = (const unsigned*)h2c;

    if (layer == 0) {
        for (int t = 0; t < TSEQ; ++t) {
            float xgv = 0.f;
            if (tid < 128) xgv = xg1[((size_t)s * TSEQ + t) * GDIM + wcol];

            if (t > 0) {
                const unsigned* p = h1u + ((size_t)(t - 1) * DIM + tid) * 4;
                uint4v u;
                do { u = poll_load16(p); }
                while (u.x == SENT || u.y == SENT || u.z == SENT || u.w == SENT);
                hA[tid] = __builtin_bit_cast(f4v, u);
            } else {
                hA[tid] = f4v{0.f, 0.f, 0.f, 0.f};
            }
            __syncthreads();

            float a0 = 0.f, a1 = 0.f, a2 = 0.f, a3 = 0.f;
            const f4v* hp = &hA[s * 32];
            #pragma unroll
            for (int r = 0; r < 32; ++r) {
                const f4v v = hp[r];
                a0 += v.x * wr[r]; a1 += v.y * wr[r];
                a2 += v.z * wr[r]; a3 += v.w * wr[r];
            }
            part[s][0][j] = a0; part[s][1][j] = a1;
            part[s][2][j] = a2; part[s][3][j] = a3;
            __syncthreads();

            if (tid < 128) {
                float sum = xgv;
                #pragma unroll
                for (int s2 = 0; s2 < 16; ++s2) sum += part[s2][s][j];
                gate_lds[s][j] = sum;
            }
            __syncthreads();

            if (tid < 32) {
                const int ub = tid >> 3, ud = tid & 7;
                const float iv = gate_lds[ub][ 0 + ud];
                const float fv = gate_lds[ub][ 8 + ud];
                const float gv = gate_lds[ub][16 + ud];
                const float ov = gate_lds[ub][24 + ud];
                const float ig = fsig(iv);
                const float fg = fsig(fv);
                const float og = fsig(ov);
                c_reg = fg * c_reg + ig * ftanh_(gv);
                const float hval = og * ftanh_(c_reg);
                __hip_atomic_store(&h1c[((size_t)t * DIM + dbase + ud) * 4 + ub],
                                   hval, __ATOMIC_RELAXED, __HIP_MEMORY_SCOPE_AGENT);
            }
        }
    } else {
        for (int t = 0; t < TSEQ; ++t) {
            if (t > 0) {
                const unsigned* p = h2u + ((size_t)(t - 1) * DIM + tid) * 4;
                uint4v u;
                do { u = poll_load16(p); }
                while (u.x == SENT || u.y == SENT || u.z == SENT || u.w == SENT);
                hB[tid] = __builtin_bit_cast(f4v, u);
            } else {
                hB[tid] = f4v{0.f, 0.f, 0.f, 0.f};
            }
            __syncthreads();

            float a0 = 0.f, a1 = 0.f, a2 = 0.f, a3 = 0.f;
            {
                const f4v* hp = &hB[s * 32];
                #pragma unroll
                for (int r = 0; r < 32; ++r) {
                    const f4v v = hp[r];
                    a0 += v.x * wr[r]; a1 += v.y * wr[r];
                    a2 += v.z * wr[r]; a3 += v.w * wr[r];
                }
            }

            {
                const unsigned* p = h1u + ((size_t)t * DIM + tid) * 4;
                uint4v u;
                do { u = poll_load16(p); }
                while (u.x == SENT || u.y == SENT || u.z == SENT || u.w == SENT);
                hA[tid] = __builtin_bit_cast(f4v, u);
            }
            __syncthreads();
            {
                const f4v* hp = &hA[s * 32];
                #pragma unroll
                for (int r = 0; r < 32; ++r) {
                    const f4v v = hp[r];
                    a0 += v.x * wx[r]; a1 += v.y * wx[r];
                    a2 += v.z * wx[r]; a3 += v.w * wx[r];
                }
            }
            part[s][0][j] = a0; part[s][1][j] = a1;
            part[s][2][j] = a2; part[s][3][j] = a3;
            __syncthreads();

            if (tid < 128) {
                float sum = bias2;
                #pragma unroll
                for (int s2 = 0; s2 < 16; ++s2) sum += part[s2][s][j];
                gate_lds[s][j] = sum;
            }
            __syncthreads();

            if (tid < 32) {
                const int ub = tid >> 3, ud = tid & 7;
                const float iv = gate_lds[ub][ 0 + ud];
                const float fv = gate_lds[ub][ 8 + ud];
                const float gv = gate_lds[ub][16 + ud];
                const float ov = gate_lds[ub][24 + ud];
                const float ig = fsig(iv);
                const float fg = fsig(fv);
                const float og = fsig(ov);
                c_reg = fg * c_reg + ig * ftanh_(gv);
                const float hval = og * ftanh_(c_reg);
                __hip_atomic_store(&h2c[((size_t)t * DIM + dbase + ud) * 4 + ub],
                                   hval, __ATOMIC_RELAXED, __HIP_MEMORY_SCOPE_AGENT);
                hs2[((size_t)ub * TSEQ + t) * DIM + dbase + ud] = hval;
            }
        }
    }
}

// ---------------------------------------------------------------------------
// W[512][32000] f32 -> W'[32000][1536] bf16 split-triples (wh, wl, wh)
// ---------------------------------------------------------------------------
__global__ __launch_bounds__(256) void transpose_W(const float* __restrict__ W,
                                                   unsigned short* __restrict__ Wt)
{
    __shared__ float tile[32][256];
    const int tid = threadIdx.x;
    const int n0 = blockIdx.x * 256;
    const int k0 = blockIdx.y * 32;

    #pragma unroll 8
    for (int r = 0; r < 32; ++r)
        tile[r][tid] = W[(size_t)(k0 + r) * VOC + n0 + tid];
    __syncthreads();

    unsigned short trip[96];
    #pragma unroll
    for (int kk = 0; kk < 32; ++kk) {
        const float w = tile[kk][tid];
        const unsigned short h = f2bf(w);
        const unsigned short l = f2bf(w - bf2f(h));
        trip[3 * kk + 0] = h;
        trip[3 * kk + 1] = l;
        trip[3 * kk + 2] = h;
    }
    unsigned short* dst = Wt + (size_t)(n0 + tid) * 1536 + 3 * k0;
    #pragma unroll
    for (int i = 0; i < 12; ++i)
        *(short8*)(dst + 8 * i) = *(short8*)&trip[8 * i];
}

// ---------------------------------------------------------------------------
// hs2[4096][512] f32 -> A'[4096][1536] bf16 split-triples (ah, ah, al)
// ---------------------------------------------------------------------------
__global__ __launch_bounds__(64) void convert_A(const float* __restrict__ A,
                                                unsigned short* __restrict__ At)
{
    const int row = blockIdx.x;
    const int tid = threadIdx.x;
    const float4 v0 = *(const float4*)&A[(size_t)row * DIM + tid * 8];
    const float4 v1 = *(const float4*)&A[(size_t)row * DIM + tid * 8 + 4];
    float vals[8] = {v0.x, v0.y, v0.z, v0.w, v1.x, v1.y, v1.z, v1.w};
    unsigned short trip[24];
    #pragma unroll
    for (int i = 0; i < 8; ++i) {
        const unsigned short h = f2bf(vals[i]);
        const unsigned short l = f2bf(vals[i] - bf2f(h));
        trip[3 * i + 0] = h;
        trip[3 * i + 1] = h;
        trip[3 * i + 2] = l;
    }
    unsigned short* dst = At + (size_t)row * 1536 + tid * 24;
    #pragma unroll
    for (int i = 0; i < 3; ++i)
        *(short8*)(dst + 8 * i) = *(short8*)&trip[8 * i];
}

// ---------------------------------------------------------------------------
// Split-bf16 MFMA logits GEMM: C[4096][32000] = A'[4096][1536]·W'^T + bias
// 128x128 tile, BK=64, 256 thr / 4 waves, 4x4 16x16x32 fragments per wave.
// LDS XOR-swizzle (slot ^= row&7) kills the stride-128B read conflict.
// ---------------------------------------------------------------------------
__global__ __launch_bounds__(256) void mfma_logits(
    const unsigned short* __restrict__ Ab, const unsigned short* __restrict__ Wb,
    const float* __restrict__ bias, float* __restrict__ C)
{
    constexpr int KP = 1536, BK = 64, NKT = KP / BK;
    __shared__ unsigned short As[128 * 64];   // phys [row][slot^ (row&7)], 16KB
    __shared__ unsigned short Bs[128 * 64];

    const int tid  = threadIdx.x;
    const int lane = tid & 63;
    const int w    = tid >> 6;
    const int wm   = w >> 1, wn = w & 1;
    const int m0 = blockIdx.y * 128;
    const int n0 = blockIdx.x * 128;

    // staging map: row = tid>>1 (global m/n row), 4 consecutive 16B slots
    const int srow = tid >> 1;
    const int s0   = (tid & 1) * 4;
    const unsigned short* gA = Ab + (size_t)(m0 + srow) * KP + s0 * 8;
    const unsigned short* gB = Wb + (size_t)(n0 + srow) * KP + s0 * 8;
    const int swz = srow & 7;

    f32x4 acc[4][4] = {};
    short8 ra[4], rb[4];

    // prologue loads (k0 = 0)
    #pragma unroll
    for (int c = 0; c < 4; ++c) {
        ra[c] = *(const short8*)(gA + c * 8);
        rb[c] = *(const short8*)(gB + c * 8);
    }

    #pragma unroll 1
    for (int kt = 0; kt < NKT; ++kt) {
        __syncthreads();
        #pragma unroll
        for (int c = 0; c < 4; ++c) {
            *(short8*)&As[srow * 64 + ((s0 + c) ^ swz) * 8] = ra[c];
            *(short8*)&Bs[srow * 64 + ((s0 + c) ^ swz) * 8] = rb[c];
        }
        __syncthreads();

        if (kt + 1 < NKT) {
            const int ko = (kt + 1) * BK;
            #pragma unroll
            for (int c = 0; c < 4; ++c) {
                ra[c] = *(const short8*)(gA + ko + c * 8);
                rb[c] = *(const short8*)(gB + ko + c * 8);
            }
        }

        #pragma unroll
        for (int kk = 0; kk < 2; ++kk) {
            const int q = kk * 4 + (lane >> 4);
            short8 a[4], b[4];
            #pragma unroll
            for (int i = 0; i < 4; ++i) {
                const int Ra = wm * 64 + i * 16 + (lane & 15);
                a[i] = *(const short8*)&As[Ra * 64 + (q ^ (Ra & 7)) * 8];
                const int Rb = wn * 64 + i * 16 + (lane & 15);
                b[i] = *(const short8*)&Bs[Rb * 64 + (q ^ (Rb & 7)) * 8];
            }
            #pragma unroll
            for (int i = 0; i < 4; ++i)
                #pragma unroll
                for (int jx = 0; jx < 4; ++jx)
                    acc[i][jx] = __builtin_amdgcn_mfma_f32_16x16x32_bf16(
                        a[i], b[jx], acc[i][jx], 0, 0, 0);
        }
    }

    // epilogue: D row = (lane>>4)*4 + r, col = lane&15  [m89-verified layout]
    float bv[4];
    #pragma unroll
    for (int jx = 0; jx < 4; ++jx)
        bv[jx] = bias[n0 + wn * 64 + jx * 16 + (lane & 15)];

    #pragma unroll
    for (int i = 0; i < 4; ++i) {
        #pragma unroll
        for (int jx = 0; jx < 4; ++jx) {
            const int col = n0 + wn * 64 + jx * 16 + (lane & 15);
            #pragma unroll
            for (int r = 0; r < 4; ++r) {
                const int row = m0 + wm * 64 + i * 16 + (lane >> 4) * 4 + r;
                C[(size_t)row * VOC + col] = acc[i][jx][r] + bv[jx];
            }
        }
    }
}

// ---------------------------------------------------------------------------
extern "C" void kernel_launch(void* const* d_in, const int* in_sizes, int n_in,
                              void* d_out, int out_size, void* d_ws, size_t ws_size,
                              hipStream_t stream)
{
    const int*   tokens = (const int*)d_in[0];
    const float* embed  = (const float*)d_in[1];
    const float* Wx0    = (const float*)d_in[2];
    const float* Wh0    = (const float*)d_in[3];
    const float* b0     = (const float*)d_in[4];
    const float* Wx1    = (const float*)d_in[5];
    const float* Wh1    = (const float*)d_in[6];
    const float* b1     = (const float*)d_in[7];
    const float* Wout   = (const float*)d_in[8];
    const float* bout   = (const float*)d_in[9];
    float* out = (float*)d_out;

    char* ws = (char*)d_ws;
    float* x   = (float*)(ws);
    float* xg1 = (float*)(ws + ((size_t)8u << 20));
    float* h1c = (float*)(ws + ((size_t)40u << 20));
    float* h2c = (float*)(ws + ((size_t)48u << 20));
    float* hs2 = x;
    unsigned short* At = (unsigned short*)(ws + ((size_t)56u << 20));
    unsigned short* Wt = (unsigned short*)(ws + ((size_t)68u << 20));

    const bool use_mfma = ws_size >= ((size_t)162u << 20);

    hipMemsetAsync(ws + ((size_t)40u << 20), 0x7F, (size_t)16u << 20, stream);

    embed_kernel<<<dim3(4096), dim3(128), 0, stream>>>(tokens, embed, x);
    gemm_bias_f32<<<dim3(16, 32), dim3(256), 0, stream>>>(x, Wx0, b0, xg1, 4096, 2048, 512);

    if (use_mfma)
        transpose_W<<<dim3(125, 16), dim3(256), 0, stream>>>(Wout, Wt);

    lstm2_kernel<<<dim3(128), dim3(512), 0, stream>>>(xg1, Wh0, Wx1, Wh1, b1, h1c, h2c, hs2);

    if (use_mfma) {
        convert_A<<<dim3(4096), dim3(64), 0, stream>>>(hs2, At);
        mfma_logits<<<dim3(250, 32), dim3(256), 0, stream>>>(At, Wt, bout, out);
    } else {
        gemm_bias_f32<<<dim3(250, 32), dim3(256), 0, stream>>>(hs2, Wout, bout, out, 4096, VOC, 512);
    }
}